// Round 13
// baseline (181.430 us; speedup 1.0000x reference)
//
#include <hip/hip_runtime.h>

// GRU via MFMA, round 13: 2-wave tiles (32 units/wave) -> <=1 wave per SIMD.
// B=128, S=144, T=50, I=10, H=64, O=1.
// Law from R5-R12: wall ~ 800cy x (waves per SIMD) per step. This kernel halves
// total waves: each wave owns TWO 16-unit blocks (18 MFMAs, 8 gate-chains with
// ILP-2); a 16-batch tile is 2 waves (128-thread wg), grid = 400 wgs ->
// 800 waves on 1024 SIMDs = at most 1 wave/SIMD. Fixed per-step overhead
// (barrier, ds latency, chain ramp) paid once per SIMD instead of twice.
// Transposed MFMA layout from R12 (A=weights, B=h/x, D: row=unit, col=batch),
// b64 h-stores, raw s_barrier, pre-scaled weights, 5-trans fused gates.
//
// MFMA 16x16x32 f16 layouts (gfx950, m89-verified):
//   A: m=lane&15, k=(lane>>4)*8+e;  B: n=lane&15, same k-map;
//   D: col=lane&15, row=(lane>>4)*4+reg.

typedef _Float16 f16;
typedef _Float16 f16x8 __attribute__((ext_vector_type(8)));
typedef _Float16 f16x4 __attribute__((ext_vector_type(4)));
typedef float    f32x4 __attribute__((ext_vector_type(4)));

constexpr int B_N = 128, S_N = 144, T_N = 50, I_N = 10, H_N = 64, G3 = 192;
constexpr int BT16 = 16, NB16 = B_N / BT16;
constexpr int HUW = 72;                 // h layout [batch16][unit64 + 8 pad] f16
constexpr int HST = 88;                 // fallback kernel stride
constexpr float L2E = 1.44269504089f;

#define MFMA16(a, b, c) __builtin_amdgcn_mfma_f32_16x16x32_f16((a), (b), (c), 0, 0, 0)

__device__ __forceinline__ float fsig(float v) {
    return __builtin_amdgcn_rcpf(1.0f + __builtin_amdgcn_exp2f(-L2E * v));
}
__device__ __forceinline__ float ftanh(float v) {
    return 1.0f - 2.0f * __builtin_amdgcn_rcpf(1.0f + __builtin_amdgcn_exp2f(2.0f * L2E * v));
}

// ---- x prep: xP[(b*S+s)*T+t][16] f16 = {x[0..9], 1.0, 0..0} ----
__global__ __launch_bounds__(256)
void pack_x(const float* __restrict__ x, f16* __restrict__ xP) {
    const int idx = blockIdx.x * 256 + threadIdx.x;
    if (idx >= B_N * S_N * T_N) return;
    const float* s = x + (size_t)idx * I_N;
    f16x8 lo, hi;
    #pragma unroll
    for (int e = 0; e < 8; ++e) lo[e] = (f16)s[e];
    hi[0] = (f16)s[8]; hi[1] = (f16)s[9]; hi[2] = (f16)1.0f;
    #pragma unroll
    for (int e = 3; e < 8; ++e) hi[e] = (f16)0.0f;
    f16* d = xP + (size_t)idx * 16;
    *(f16x8*)d = lo; *(f16x8*)(d + 8) = hi;
}

// ---- 2-block wave step: 18 MFMAs, 8 gate-chains (ILP 2), 2x b64 stores ----
// h' = [ (eC-1)*eB + h*(1+eC) ] * rcp( (1+eC)*(1+eB) )
#define STEPW2(ss, xf)                                                            \
    {                                                                             \
        const int cur = (ss) & 1, nxt = cur ^ 1;                                  \
        const f16x8 xB = xf;                                                      \
        if ((ss) + 2 < S_N && lg < 2)                                             \
            xf = *(const f16x8*)(xProw + (size_t)((ss) + 2) * (T_N * 16) + lg * 8); \
        const f16* hrow = &hL[cur][lc][0];                                        \
        const f16x8 hB0 = *(const f16x8*)(hrow + lg * 8);                         \
        const f16x8 hB1 = *(const f16x8*)(hrow + 32 + lg * 8);                    \
        f32x4 aR[2], aZ[2], aNH[2], aNX[2];                                       \
        _Pragma("unroll")                                                         \
        for (int b = 0; b < 2; ++b) {                                             \
            const f32x4 zv = {0.f, 0.f, 0.f, 0.f};                                \
            aR[b]  = MFMA16(WxR[b], xB, zv);                                      \
            aZ[b]  = MFMA16(WxZ[b], xB, zv);                                      \
            aNX[b] = MFMA16(WxN[b], xB, zv);                                      \
            aNH[b] = zv;                                                          \
        }                                                                         \
        _Pragma("unroll")                                                         \
        for (int b = 0; b < 2; ++b) {                                             \
            aR[b]  = MFMA16(WhR0[b], hB0, aR[b]);                                 \
            aR[b]  = MFMA16(WhR1[b], hB1, aR[b]);                                 \
            aZ[b]  = MFMA16(WhZ0[b], hB0, aZ[b]);                                 \
            aZ[b]  = MFMA16(WhZ1[b], hB1, aZ[b]);                                 \
            aNH[b] = MFMA16(WhN0[b], hB0, aNH[b]);                                \
            aNH[b] = MFMA16(WhN1[b], hB1, aNH[b]);                                \
        }                                                                         \
        _Pragma("unroll")                                                         \
        for (int b = 0; b < 2; ++b) {                                             \
            f16x4 hv;                                                             \
            _Pragma("unroll")                                                     \
            for (int j = 0; j < 4; ++j) {                                         \
                const float eA = __builtin_amdgcn_exp2f(aR[b][j]);                \
                const float rr = __builtin_amdgcn_rcpf(1.0f + eA);                \
                const float eB = __builtin_amdgcn_exp2f(aZ[b][j]);                \
                const float eC = __builtin_amdgcn_exp2f(fmaf(rr, aNH[b][j] + bnhs4[b][j], aNX[b][j])); \
                const float v  = 1.0f + eC;                                       \
                const float ip = __builtin_amdgcn_rcpf(v * (1.0f + eB));          \
                const float p  = (eC - 1.0f) * eB;                                \
                ho[b][j] = fmaf(ho[b][j], v, p) * ip;                             \
                hv[j] = (f16)ho[b][j];                                            \
            }                                                                     \
            *(f16x4*)(&hL[nxt][lc][w * 32 + b * 16 + lg * 4]) = hv;               \
        }                                                                         \
        asm volatile("s_waitcnt lgkmcnt(0)" ::: "memory");                        \
        __builtin_amdgcn_s_barrier();                                             \
        asm volatile("" ::: "memory");                                            \
    }

__global__ __launch_bounds__(128, 1)
void gru_w2(const f16* __restrict__ xP, const float* __restrict__ x,
            const float* __restrict__ Wih_f, const float* __restrict__ Whh_f,
            const float* __restrict__ bih_f, const float* __restrict__ bhh_f,
            const float* __restrict__ Wih_b, const float* __restrict__ bih_b,
            const float* __restrict__ bhh_b,
            const float* __restrict__ Wfc,   const float* __restrict__ bfc,
            float* __restrict__ out)
{
    __shared__ f16   hL[2][BT16][HUW];      // 4.6 KB h double buffer [batch][unit]
    __shared__ float hfL[BT16][68];         // epilogue fwd h (f32)
    __shared__ float hbL[BT16][68];         // epilogue bwd h (f32)

    const int tid = threadIdx.x;
    const int w   = tid >> 6, l = tid & 63;   // wave 0: units 0-31; wave 1: units 32-63
    const int lc  = l & 15;            // m (unit-in-tile) for A; n (batch) for B/D-col
    const int lg  = l >> 4;            // k-group
    const int t   = blockIdx.x >> 3;           // turbine 0..49
    const int b0  = (blockIdx.x & 7) * BT16;   // batch tile base

    // ---------------- prologue ----------------
    {
        f16* hp = &hL[0][0][0];
        for (int i = tid; i < 2 * BT16 * HUW; i += 128) hp[i] = (f16)0.0f;   // h0 = 0
    }

    const float* Whh = Whh_f + (size_t)t * G3 * H_N;
    const float* Wih = Wih_f + (size_t)t * G3 * I_N;
    const f16* xProw = xP + ((size_t)(b0 + lc) * S_N * T_N + t) * 16;

    // weight A-fragments for BOTH unit-blocks of this wave, pre-scaled:
    // r,z by -log2e; n by +2log2e
    const float sRZ = -L2E, sN = 2.0f * L2E;
    auto loadWh = [&](int g, int kk, float sc) -> f16x8 {
        const float4* p = (const float4*)(Whh + (size_t)g * H_N + kk * 32 + lg * 8);
        const float4 a = p[0], b = p[1];
        f16x8 v;
        v[0] = (f16)(sc * a.x); v[1] = (f16)(sc * a.y); v[2] = (f16)(sc * a.z); v[3] = (f16)(sc * a.w);
        v[4] = (f16)(sc * b.x); v[5] = (f16)(sc * b.y); v[6] = (f16)(sc * b.z); v[7] = (f16)(sc * b.w);
        return v;
    };
    auto loadWx = [&](int g, bool rz, float sc) -> f16x8 {
        f16x8 v;
        #pragma unroll
        for (int j = 0; j < 8; ++j) {
            const int k = lg * 8 + j;
            float val = 0.0f;
            if (k < I_N)       val = Wih[(size_t)g * I_N + k];
            else if (k == 10)  val = bih_f[t * G3 + g] + (rz ? bhh_f[t * G3 + g] : 0.0f);
            v[j] = (f16)(sc * val);
        }
        return v;
    };

    f16x8 WhR0[2], WhR1[2], WhZ0[2], WhZ1[2], WhN0[2], WhN1[2];
    f16x8 WxR[2], WxZ[2], WxN[2];
    float bnhs4[2][4];
    #pragma unroll
    for (int b = 0; b < 2; ++b) {
        const int u = w * 32 + b * 16 + lc;        // this lane's unit (A-row m = lc)
        WhR0[b] = loadWh(u, 0, sRZ);        WhR1[b] = loadWh(u, 1, sRZ);
        WhZ0[b] = loadWh(64 + u, 0, sRZ);   WhZ1[b] = loadWh(64 + u, 1, sRZ);
        WhN0[b] = loadWh(128 + u, 0, sN);   WhN1[b] = loadWh(128 + u, 1, sN);
        WxR[b]  = loadWx(u, true, sRZ);
        WxZ[b]  = loadWx(64 + u, true, sRZ);
        WxN[b]  = loadWx(128 + u, false, sN);
        const float4 bb = *(const float4*)(bhh_f + (size_t)t * G3 + 128 + w * 32 + b * 16 + lg * 4);
        bnhs4[b][0] = sN * bb.x; bnhs4[b][1] = sN * bb.y;
        bnhs4[b][2] = sN * bb.z; bnhs4[b][3] = sN * bb.w;
    }

    // x B-fragments, depth 2 (lanes lg>=2 keep zeros; k slots 16..31 are zero)
    f16x8 xsA, xsB;
    #pragma unroll
    for (int e = 0; e < 8; ++e) { xsA[e] = (f16)0.0f; xsB[e] = (f16)0.0f; }
    if (lg < 2) {
        xsA = *(const f16x8*)(xProw + lg * 8);
        xsB = *(const f16x8*)(xProw + (size_t)(T_N * 16) + lg * 8);
    }

    float ho[2][4] = {{0.f,0.f,0.f,0.f},{0.f,0.f,0.f,0.f}};  // units w*32+b*16+lg*4+j, batch lc

    __syncthreads();

    // ---------------- scan ----------------
    for (int s = 0; s < S_N; s += 2) {
        STEPW2(s,     xsA)
        STEPW2(s + 1, xsB)
    }

    // ---------------- epilogue ----------------
    #pragma unroll
    for (int b = 0; b < 2; ++b) {
        f32x4 hv = {ho[b][0], ho[b][1], ho[b][2], ho[b][3]};
        *(f32x4*)(&hfL[lc][w * 32 + b * 16 + lg * 4]) = hv;
    }

    // backward cell: single step from h0=0 (=> Whh_b unused), on x[:, S-1, :].
    // 16 rows; 8 threads/row, 8 units each.
    {
        const int row2 = tid >> 3;          // 0..15
        const int j0   = (tid & 7) * 8;
        const float* wib = Wih_b + (size_t)t * G3 * I_N;
        const float* bib = bih_b + t * G3;
        const float* bhb = bhh_b + t * G3;
        float2 xr[5];
        const float2* xp2 = (const float2*)(x + (((size_t)(b0 + row2) * S_N + (S_N - 1)) * T_N + t) * I_N);
        #pragma unroll
        for (int k = 0; k < 5; ++k) xr[k] = xp2[k];
        #pragma unroll
        for (int m = 0; m < 8; ++m) {
            const int j = j0 + m;
            float ir = bib[j], iz = bib[64 + j], inn = bib[128 + j];
            const float2* wr = (const float2*)(wib + (size_t)j * I_N);
            const float2* wz = (const float2*)(wib + (size_t)(64 + j) * I_N);
            const float2* wn = (const float2*)(wib + (size_t)(128 + j) * I_N);
            #pragma unroll
            for (int k = 0; k < 5; ++k) {
                ir  = fmaf(wr[k].x, xr[k].x, fmaf(wr[k].y, xr[k].y, ir));
                iz  = fmaf(wz[k].x, xr[k].x, fmaf(wz[k].y, xr[k].y, iz));
                inn = fmaf(wn[k].x, xr[k].x, fmaf(wn[k].y, xr[k].y, inn));
            }
            const float r  = fsig(ir + bhb[j]);
            const float z  = fsig(iz + bhb[64 + j]);
            const float nn = ftanh(inn + r * bhb[128 + j]);
            hbL[row2][j] = (1.0f - z) * nn;   // h0 = 0
        }
    }
    __syncthreads();

    // FC: out[b,0,t] = [hf|hb] . Wfc[t,0,:] + bfc[t]
    if (tid < BT16) {
        const float* wfc = Wfc + (size_t)t * 2 * H_N;
        float acc = bfc[t];
        #pragma unroll 4
        for (int j = 0; j < H_N; ++j) acc += hfL[tid][j] * wfc[j];
        #pragma unroll 4
        for (int j = 0; j < H_N; ++j) acc += hbL[tid][j] * wfc[64 + j];
        out[(size_t)(b0 + tid) * T_N + t] = acc;
    }
}

// ================= fallback (no workspace): round-5 single-stream, raw x loads =================

#define LOADX_R(ss, q0, q1, q2, q3, q4)                                           \
    if ((ss) < S_N) {                                                             \
        const float* _p = x + (((size_t)(b0 + lc) * S_N + (ss)) * T_N + t) * I_N; \
        if (lg == 0) {                                                            \
            q0 = *(const float2*)(_p);     q1 = *(const float2*)(_p + 2);         \
            q2 = *(const float2*)(_p + 4); q3 = *(const float2*)(_p + 6);         \
        } else if (lg == 1) {                                                     \
            q4 = *(const float2*)(_p + 8);                                        \
        }                                                                         \
    }

#define STEP1(ss, q0, q1, q2, q3, q4)                                             \
    {                                                                             \
        const int cur = (ss) & 1, nxt = cur ^ 1;                                  \
        const f16* hrow = &hL[cur][lc][0];                                        \
        const f16x8 hA0 = *(const f16x8*)(hrow + lg * 8);                         \
        const f16x8 hA1 = *(const f16x8*)(hrow + 32 + lg * 8);                    \
        f16x8 xA;                                                                 \
        _Pragma("unroll")                                                         \
        for (int e = 0; e < 8; ++e) xA[e] = (f16)0.0f;                            \
        if (lg == 0) {                                                            \
            xA[0] = (f16)q0.x; xA[1] = (f16)q0.y; xA[2] = (f16)q1.x; xA[3] = (f16)q1.y; \
            xA[4] = (f16)q2.x; xA[5] = (f16)q2.y; xA[6] = (f16)q3.x; xA[7] = (f16)q3.y; \
        } else if (lg == 1) {                                                     \
            xA[0] = (f16)q4.x; xA[1] = (f16)q4.y; xA[2] = (f16)1.0f;              \
        }                                                                         \
        LOADX_R((ss) + 2, q0, q1, q2, q3, q4)                                     \
        f32x4 aR  = {0,0,0,0}, aZ = {0,0,0,0}, aNH = {0,0,0,0}, aNX = {0,0,0,0};  \
        aR  = MFMA16(xA,  BxR,  aR);                                              \
        aZ  = MFMA16(xA,  BxZ,  aZ);                                              \
        aNX = MFMA16(xA,  BxN,  aNX);                                             \
        aR  = MFMA16(hA0, BhR0, aR);                                              \
        aR  = MFMA16(hA1, BhR1, aR);                                              \
        aZ  = MFMA16(hA0, BhZ0, aZ);                                              \
        aZ  = MFMA16(hA1, BhZ1, aZ);                                              \
        aNH = MFMA16(hA0, BhN0, aNH);                                             \
        aNH = MFMA16(hA1, BhN1, aNH);                                             \
        const int r0 = lg * 4;                                                    \
        _Pragma("unroll")                                                         \
        for (int j = 0; j < 4; ++j) {                                             \
            const float rr = __builtin_amdgcn_rcpf(1.0f + __builtin_amdgcn_exp2f(aR[j])); \
            const float zz = __builtin_amdgcn_rcpf(1.0f + __builtin_amdgcn_exp2f(aZ[j])); \
            const float qq = __builtin_amdgcn_rcpf(1.0f + __builtin_amdgcn_exp2f(fmaf(rr, aNH[j] + bnhs, aNX[j]))); \
            const float nn = fmaf(-2.0f, qq, 1.0f);                               \
            ho[j] = fmaf(zz, ho[j] - nn, nn);                                     \
            hL[nxt][r0 + j][uc + lc] = (f16)ho[j];                                \
        }                                                                         \
        asm volatile("s_waitcnt lgkmcnt(0)" ::: "memory");                        \
        __builtin_amdgcn_s_barrier();                                             \
        asm volatile("" ::: "memory");                                            \
    }

__global__ __launch_bounds__(256, 2)
void gru_mfma1(const float* __restrict__ x,
               const float* __restrict__ Wih_f, const float* __restrict__ Whh_f,
               const float* __restrict__ bih_f, const float* __restrict__ bhh_f,
               const float* __restrict__ Wih_b, const float* __restrict__ bih_b,
               const float* __restrict__ bhh_b,
               const float* __restrict__ Wfc,   const float* __restrict__ bfc,
               float* __restrict__ out)
{
    __shared__ f16   hL[2][BT16][HST];
    __shared__ float hfL[BT16][H_N + 1];
    __shared__ float hbL[BT16][H_N + 1];

    const int tid = threadIdx.x;
    const int w   = tid >> 6, l = tid & 63;
    const int uc  = w * 16;
    const int lc  = l & 15;
    const int lg  = l >> 4;
    const int t   = blockIdx.x / NB16;
    const int b0  = (blockIdx.x % NB16) * BT16;

    {
        f16* hp = &hL[0][0][0];
        for (int i = tid; i < 2 * BT16 * HST; i += 256) hp[i] = (f16)0.0f;
    }

    const float* Whh = Whh_f + (size_t)t * G3 * H_N;
    const float* Wih = Wih_f + (size_t)t * G3 * I_N;

    const float sRZ = -L2E, sN = 2.0f * L2E;
    auto loadBh = [&](int g, int kk, float sc) -> f16x8 {
        const float4* p = (const float4*)(Whh + (size_t)g * H_N + kk * 32 + lg * 8);
        const float4 a = p[0], b = p[1];
        f16x8 v;
        v[0] = (f16)(sc * a.x); v[1] = (f16)(sc * a.y); v[2] = (f16)(sc * a.z); v[3] = (f16)(sc * a.w);
        v[4] = (f16)(sc * b.x); v[5] = (f16)(sc * b.y); v[6] = (f16)(sc * b.z); v[7] = (f16)(sc * b.w);
        return v;
    };
    auto loadBx = [&](int g, bool rz, float sc) -> f16x8 {
        f16x8 v;
        #pragma unroll
        for (int j = 0; j < 8; ++j) {
            const int k = lg * 8 + j;
            float val = 0.0f;
            if (k < I_N)       val = Wih[(size_t)g * I_N + k];
            else if (k == 10)  val = bih_f[t * G3 + g] + (rz ? bhh_f[t * G3 + g] : 0.0f);
            v[j] = (f16)(sc * val);
        }
        return v;
    };

    const f16x8 BhR0 = loadBh(uc + lc, 0, sRZ),        BhR1 = loadBh(uc + lc, 1, sRZ);
    const f16x8 BhZ0 = loadBh(64 + uc + lc, 0, sRZ),   BhZ1 = loadBh(64 + uc + lc, 1, sRZ);
    const f16x8 BhN0 = loadBh(128 + uc + lc, 0, sN),   BhN1 = loadBh(128 + uc + lc, 1, sN);
    const f16x8 BxR  = loadBx(uc + lc, true, sRZ);
    const f16x8 BxZ  = loadBx(64 + uc + lc, true, sRZ);
    const f16x8 BxN  = loadBx(128 + uc + lc, false, sN);
    const float bnhs = sN * bhh_f[t * G3 + 128 + uc + lc];

    float2 ra0 = {0.f,0.f}, ra1 = {0.f,0.f}, ra2 = {0.f,0.f}, ra3 = {0.f,0.f}, ra4 = {0.f,0.f};
    float2 rb0 = {0.f,0.f}, rb1 = {0.f,0.f}, rb2 = {0.f,0.f}, rb3 = {0.f,0.f}, rb4 = {0.f,0.f};
    LOADX_R(0, ra0, ra1, ra2, ra3, ra4)
    LOADX_R(1, rb0, rb1, rb2, rb3, rb4)

    float ho[4] = {0.f, 0.f, 0.f, 0.f};

    __syncthreads();

    for (int s = 0; s < S_N; s += 2) {
        STEP1(s,     ra0, ra1, ra2, ra3, ra4)
        STEP1(s + 1, rb0, rb1, rb2, rb3, rb4)
    }

    {
        const int r0 = lg * 4;
        #pragma unroll
        for (int j = 0; j < 4; ++j) hfL[r0 + j][uc + lc] = ho[j];
    }

    {
        const int row2 = tid >> 4;
        const int j0   = (tid & 15) * 4;
        const float* wib = Wih_b + (size_t)t * G3 * I_N;
        const float* bib = bih_b + t * G3;
        const float* bhb = bhh_b + t * G3;
        float xr[I_N];
        #pragma unroll
        for (int k = 0; k < I_N; ++k)
            xr[k] = x[(((size_t)(b0 + row2) * S_N + (S_N - 1)) * T_N + t) * I_N + k];
        #pragma unroll
        for (int m = 0; m < 4; ++m) {
            const int j = j0 + m;
            float ir = bib[j], iz = bib[64 + j], inn = bib[128 + j];
            #pragma unroll
            for (int k = 0; k < I_N; ++k) {
                const float xv = xr[k];
                ir  += wib[(size_t)j * I_N + k]          * xv;
                iz  += wib[(size_t)(64 + j) * I_N + k]   * xv;
                inn += wib[(size_t)(128 + j) * I_N + k]  * xv;
            }
            const float r  = fsig(ir + bhb[j]);
            const float z  = fsig(iz + bhb[64 + j]);
            const float nn = ftanh(inn + r * bhb[128 + j]);
            hbL[row2][j] = (1.0f - z) * nn;
        }
    }
    __syncthreads();

    if (tid < BT16) {
        const float* wfc = Wfc + (size_t)t * 2 * H_N;
        float acc = bfc[t];
        #pragma unroll 4
        for (int j = 0; j < H_N; ++j) acc += hfL[tid][j] * wfc[j];
        #pragma unroll 4
        for (int j = 0; j < H_N; ++j) acc += hbL[tid][j] * wfc[64 + j];
        out[(size_t)(b0 + tid) * T_N + t] = acc;
    }
}

extern "C" void kernel_launch(void* const* d_in, const int* in_sizes, int n_in,
                              void* d_out, int out_size, void* d_ws, size_t ws_size,
                              hipStream_t stream) {
    const float* x     = (const float*)d_in[0];
    const float* Wih_f = (const float*)d_in[1];
    const float* Whh_f = (const float*)d_in[2];
    const float* bih_f = (const float*)d_in[3];
    const float* bhh_f = (const float*)d_in[4];
    const float* Wih_b = (const float*)d_in[5];
    // d_in[6] = Whh_b: unused (backward cell runs one step from h0 == 0).
    const float* bih_b = (const float*)d_in[7];
    const float* bhh_b = (const float*)d_in[8];
    const float* Wfc   = (const float*)d_in[9];
    const float* bfc   = (const float*)d_in[10];
    float* out = (float*)d_out;

    const size_t xp_bytes = (size_t)B_N * S_N * T_N * 16 * sizeof(f16);  // 29.5 MB

    if (ws_size >= xp_bytes) {
        f16* xP = (f16*)d_ws;
        const int n = B_N * S_N * T_N;
        hipLaunchKernelGGL(pack_x, dim3((n + 255) / 256), dim3(256), 0, stream, x, xP);
        hipLaunchKernelGGL(gru_w2, dim3(T_N * NB16), dim3(128), 0, stream,
                           xP, x, Wih_f, Whh_f, bih_f, bhh_f, Wih_b, bih_b, bhh_b, Wfc, bfc, out);
    } else {
        hipLaunchKernelGGL(gru_mfma1, dim3(T_N * NB16), dim3(256), 0, stream,
                           x, Wih_f, Whh_f, bih_f, bhh_f, Wih_b, bih_b, bhh_b, Wfc, bfc, out);
    }
}

// Round 14
// 105.901 us; speedup vs baseline: 1.7132x; 1.7132x over previous
//
#include <hip/hip_runtime.h>

// GRU via MFMA, round 14: R12 (best, 94us profiled) with inline raw x loads --
// eliminates the pack_x pre-pass (~65MB HBM traffic, ~6-10us of harness time).
// B=128, S=144, T=50, I=10, H=64, O=1.
// Grid = T * (B/32) = 200 wgs x 512 threads (8 waves), uniform <=1 wg/CU.
// Transposed MFMA: A = weights (m = gate-unit), B = h/x (n = batch),
// D: row = unit, col = batch -> h-update store is one ds_write_b64.
// Weights+biases pre-scaled (r,z by -log2e; n by +2log2e) so exp2 args come
// straight from the accumulators; 5-trans fused gates; f16 h double buffer;
// raw s_barrier + lgkmcnt-only wait (x loads stay in flight across barriers);
// x prefetched depth-2 into named float2 registers, cvt'd to f16 at use.
//
// MFMA 16x16x32 f16 layouts (gfx950, m89-verified):
//   A: m=lane&15, k=(lane>>4)*8+e;  B: n=lane&15, same k-map;
//   D: col=lane&15, row=(lane>>4)*4+reg.

typedef _Float16 f16;
typedef _Float16 f16x8 __attribute__((ext_vector_type(8)));
typedef _Float16 f16x4 __attribute__((ext_vector_type(4)));
typedef float    f32x4 __attribute__((ext_vector_type(4)));

constexpr int B_N = 128, S_N = 144, T_N = 50, I_N = 10, H_N = 64, G3 = 192;
constexpr int BT16 = 16;
constexpr int HUW = 72;                 // h layout [batch16][unit64 + 8 pad] f16
constexpr float L2E = 1.44269504089f;

#define MFMA16(a, b, c) __builtin_amdgcn_mfma_f32_16x16x32_f16((a), (b), (c), 0, 0, 0)

__device__ __forceinline__ float fsig(float v) {
    return __builtin_amdgcn_rcpf(1.0f + __builtin_amdgcn_exp2f(-L2E * v));
}
__device__ __forceinline__ float ftanh(float v) {
    return 1.0f - 2.0f * __builtin_amdgcn_rcpf(1.0f + __builtin_amdgcn_exp2f(2.0f * L2E * v));
}

// issue raw x loads for step (ss) into named float2 regs (lg0: q0..q3, lg1: q4)
#define LOADX_R(ss, q0, q1, q2, q3, q4)                                           \
    if ((ss) < S_N) {                                                             \
        const float* _p = x + (((size_t)(b0 + lc) * S_N + (ss)) * T_N + t) * I_N; \
        if (lg == 0) {                                                            \
            q0 = *(const float2*)(_p);     q1 = *(const float2*)(_p + 2);         \
            q2 = *(const float2*)(_p + 4); q3 = *(const float2*)(_p + 6);         \
        } else if (lg == 1) {                                                     \
            q4 = *(const float2*)(_p + 8);                                        \
        }                                                                         \
    }

// ---- transposed paired-tile step: 9 MFMAs (weights in A slot), b64 h-store ----
// h' = [ (eC-1)*eB + h*(1+eC) ] * rcp( (1+eC)*(1+eB) )
#define STEPT(ss, q0, q1, q2, q3, q4)                                             \
    {                                                                             \
        const int cur = (ss) & 1, nxt = cur ^ 1;                                  \
        f16x8 xB;                                                                 \
        _Pragma("unroll")                                                         \
        for (int e = 0; e < 8; ++e) xB[e] = (f16)0.0f;                            \
        if (lg == 0) {                                                            \
            xB[0] = (f16)q0.x; xB[1] = (f16)q0.y; xB[2] = (f16)q1.x; xB[3] = (f16)q1.y; \
            xB[4] = (f16)q2.x; xB[5] = (f16)q2.y; xB[6] = (f16)q3.x; xB[7] = (f16)q3.y; \
        } else if (lg == 1) {                                                     \
            xB[0] = (f16)q4.x; xB[1] = (f16)q4.y; xB[2] = (f16)1.0f;              \
        }                                                                         \
        LOADX_R((ss) + 2, q0, q1, q2, q3, q4)                                     \
        const f16* hrow = &hL[tile][cur][lc][0];                                  \
        const f16x8 hB0 = *(const f16x8*)(hrow + lg * 8);                         \
        const f16x8 hB1 = *(const f16x8*)(hrow + 32 + lg * 8);                    \
        f32x4 aR  = {0,0,0,0}, aZ = {0,0,0,0}, aNH = {0,0,0,0}, aNX = {0,0,0,0};  \
        aR  = MFMA16(WxR,  xB,  aR);                                              \
        aZ  = MFMA16(WxZ,  xB,  aZ);                                              \
        aNX = MFMA16(WxN,  xB,  aNX);                                             \
        aR  = MFMA16(WhR0, hB0, aR);                                              \
        aR  = MFMA16(WhR1, hB1, aR);                                              \
        aZ  = MFMA16(WhZ0, hB0, aZ);                                              \
        aZ  = MFMA16(WhZ1, hB1, aZ);                                              \
        aNH = MFMA16(WhN0, hB0, aNH);                                             \
        aNH = MFMA16(WhN1, hB1, aNH);                                             \
        f16x4 hv;                                                                 \
        _Pragma("unroll")                                                         \
        for (int j = 0; j < 4; ++j) {                                             \
            const float eA = __builtin_amdgcn_exp2f(aR[j]);                       \
            const float rr = __builtin_amdgcn_rcpf(1.0f + eA);                    \
            const float eB = __builtin_amdgcn_exp2f(aZ[j]);                       \
            const float eC = __builtin_amdgcn_exp2f(fmaf(rr, aNH[j] + bnhs4[j], aNX[j])); \
            const float v  = 1.0f + eC;                                           \
            const float ip = __builtin_amdgcn_rcpf(v * (1.0f + eB));              \
            const float p  = (eC - 1.0f) * eB;                                    \
            ho[j] = fmaf(ho[j], v, p) * ip;                                       \
            hv[j] = (f16)ho[j];                                                   \
        }                                                                         \
        *(f16x4*)(&hL[tile][nxt][lc][uc + lg * 4]) = hv;                          \
        asm volatile("s_waitcnt lgkmcnt(0)" ::: "memory");                        \
        __builtin_amdgcn_s_barrier();                                             \
        asm volatile("" ::: "memory");                                            \
    }

__global__ __launch_bounds__(512, 1)
void gru_tr(const float* __restrict__ x,
            const float* __restrict__ Wih_f, const float* __restrict__ Whh_f,
            const float* __restrict__ bih_f, const float* __restrict__ bhh_f,
            const float* __restrict__ Wih_b, const float* __restrict__ bih_b,
            const float* __restrict__ bhh_b,
            const float* __restrict__ Wfc,   const float* __restrict__ bfc,
            float* __restrict__ out)
{
    __shared__ f16   hL[2][2][BT16][HUW];   // [tile][buf][batch row][unit] 9.2 KB
    __shared__ float hfL[2 * BT16][68];     // epilogue fwd h (f32), 16B-aligned rows
    __shared__ float hbL[2 * BT16][68];     // epilogue bwd h (f32)

    const int tid  = threadIdx.x;
    const int w    = tid >> 6, l = tid & 63;
    const int tile = w >> 2;            // 0 = rows b0.., 1 = rows b0+16..
    const int uc   = (w & 3) * 16;      // unit-block base 0,16,32,48
    const int lc   = l & 15;            // m (gate unit) for A; n (batch) for B/D-col
    const int lg   = l >> 4;            // k-group
    const int t    = blockIdx.x >> 2;          // turbine 0..49
    const int b0   = (blockIdx.x & 3) * 32 + tile * 16;

    // ---------------- prologue ----------------
    {
        f16* hp = &hL[0][0][0][0];
        for (int i = tid; i < 2 * 2 * BT16 * HUW; i += 512) hp[i] = (f16)0.0f;   // h0 = 0
    }

    const float* Whh = Whh_f + (size_t)t * G3 * H_N;
    const float* Wih = Wih_f + (size_t)t * G3 * I_N;

    // weight A-fragments (lane holds W[g0+lc][k=lg*8+e]), pre-scaled:
    // r,z by -log2e; n by +2log2e
    const float sRZ = -L2E, sN = 2.0f * L2E;
    auto loadWh = [&](int g, int kk, float sc) -> f16x8 {
        const float4* p = (const float4*)(Whh + (size_t)g * H_N + kk * 32 + lg * 8);
        const float4 a = p[0], b = p[1];
        f16x8 v;
        v[0] = (f16)(sc * a.x); v[1] = (f16)(sc * a.y); v[2] = (f16)(sc * a.z); v[3] = (f16)(sc * a.w);
        v[4] = (f16)(sc * b.x); v[5] = (f16)(sc * b.y); v[6] = (f16)(sc * b.z); v[7] = (f16)(sc * b.w);
        return v;
    };
    auto loadWx = [&](int g, bool rz, float sc) -> f16x8 {
        f16x8 v;
        #pragma unroll
        for (int j = 0; j < 8; ++j) {
            const int k = lg * 8 + j;
            float val = 0.0f;
            if (k < I_N)       val = Wih[(size_t)g * I_N + k];
            else if (k == 10)  val = bih_f[t * G3 + g] + (rz ? bhh_f[t * G3 + g] : 0.0f);
            v[j] = (f16)(sc * val);
        }
        return v;
    };

    const f16x8 WhR0 = loadWh(uc + lc, 0, sRZ),        WhR1 = loadWh(uc + lc, 1, sRZ);
    const f16x8 WhZ0 = loadWh(64 + uc + lc, 0, sRZ),   WhZ1 = loadWh(64 + uc + lc, 1, sRZ);
    const f16x8 WhN0 = loadWh(128 + uc + lc, 0, sN),   WhN1 = loadWh(128 + uc + lc, 1, sN);
    const f16x8 WxR  = loadWx(uc + lc, true, sRZ);
    const f16x8 WxZ  = loadWx(64 + uc + lc, true, sRZ);
    const f16x8 WxN  = loadWx(128 + uc + lc, false, sN);

    // n-gate hidden bias, per D-row (unit uc + lg*4 + j)
    float bnhs4[4];
    {
        const float4 bb = *(const float4*)(bhh_f + (size_t)t * G3 + 128 + uc + lg * 4);
        bnhs4[0] = sN * bb.x; bnhs4[1] = sN * bb.y; bnhs4[2] = sN * bb.z; bnhs4[3] = sN * bb.w;
    }

    // x prefetch registers, depth 2 (named scalars; lanes lg>=2 never load)
    float2 ra0 = {0.f,0.f}, ra1 = {0.f,0.f}, ra2 = {0.f,0.f}, ra3 = {0.f,0.f}, ra4 = {0.f,0.f};
    float2 rb0 = {0.f,0.f}, rb1 = {0.f,0.f}, rb2 = {0.f,0.f}, rb3 = {0.f,0.f}, rb4 = {0.f,0.f};
    LOADX_R(0, ra0, ra1, ra2, ra3, ra4)
    LOADX_R(1, rb0, rb1, rb2, rb3, rb4)

    float ho[4] = {0.f, 0.f, 0.f, 0.f};   // lane's h: units uc+lg*4+j, batch row lc

    __syncthreads();

    // ---------------- scan ----------------
    for (int s = 0; s < S_N; s += 2) {
        STEPT(s,     ra0, ra1, ra2, ra3, ra4)
        STEPT(s + 1, rb0, rb1, rb2, rb3, rb4)
    }

    // ---------------- epilogue ----------------
    {
        f32x4 hv = {ho[0], ho[1], ho[2], ho[3]};
        *(f32x4*)(&hfL[tile * BT16 + lc][uc + lg * 4]) = hv;
    }

    // backward cell: single step from h0=0 (=> Whh_b unused), on x[:, S-1, :].
    // 32 rows of this wg's batch quad; 16 threads/row, 4 units each.
    {
        const int row2 = tid >> 4;          // 0..31
        const int j0   = (tid & 15) * 4;
        const int bq   = (blockIdx.x & 3) * 32;
        const float* wib = Wih_b + (size_t)t * G3 * I_N;
        const float* bib = bih_b + t * G3;
        const float* bhb = bhh_b + t * G3;
        float2 xr[5];
        const float2* xp2 = (const float2*)(x + (((size_t)(bq + row2) * S_N + (S_N - 1)) * T_N + t) * I_N);
        #pragma unroll
        for (int k = 0; k < 5; ++k) xr[k] = xp2[k];
        #pragma unroll
        for (int m = 0; m < 4; ++m) {
            const int j = j0 + m;
            float ir = bib[j], iz = bib[64 + j], inn = bib[128 + j];
            const float2* wr = (const float2*)(wib + (size_t)j * I_N);
            const float2* wz = (const float2*)(wib + (size_t)(64 + j) * I_N);
            const float2* wn = (const float2*)(wib + (size_t)(128 + j) * I_N);
            #pragma unroll
            for (int k = 0; k < 5; ++k) {
                ir  = fmaf(wr[k].x, xr[k].x, fmaf(wr[k].y, xr[k].y, ir));
                iz  = fmaf(wz[k].x, xr[k].x, fmaf(wz[k].y, xr[k].y, iz));
                inn = fmaf(wn[k].x, xr[k].x, fmaf(wn[k].y, xr[k].y, inn));
            }
            const float r  = fsig(ir + bhb[j]);
            const float z  = fsig(iz + bhb[64 + j]);
            const float nn = ftanh(inn + r * bhb[128 + j]);
            hbL[row2][j] = (1.0f - z) * nn;   // h0 = 0
        }
    }
    __syncthreads();

    // FC: out[b,0,t] = [hf|hb] . Wfc[t,0,:] + bfc[t]
    if (tid < 2 * BT16) {
        const int bq = (blockIdx.x & 3) * 32;
        const float* wfc = Wfc + (size_t)t * 2 * H_N;
        float acc = bfc[t];
        #pragma unroll 4
        for (int j = 0; j < H_N; ++j) acc += hfL[tid][j] * wfc[j];
        #pragma unroll 4
        for (int j = 0; j < H_N; ++j) acc += hbL[tid][j] * wfc[64 + j];
        out[(size_t)(bq + tid) * T_N + t] = acc;
    }
}

extern "C" void kernel_launch(void* const* d_in, const int* in_sizes, int n_in,
                              void* d_out, int out_size, void* d_ws, size_t ws_size,
                              hipStream_t stream) {
    const float* x     = (const float*)d_in[0];
    const float* Wih_f = (const float*)d_in[1];
    const float* Whh_f = (const float*)d_in[2];
    const float* bih_f = (const float*)d_in[3];
    const float* bhh_f = (const float*)d_in[4];
    const float* Wih_b = (const float*)d_in[5];
    // d_in[6] = Whh_b: unused (backward cell runs one step from h0 == 0).
    const float* bih_b = (const float*)d_in[7];
    const float* bhh_b = (const float*)d_in[8];
    const float* Wfc   = (const float*)d_in[9];
    const float* bfc   = (const float*)d_in[10];
    float* out = (float*)d_out;

    hipLaunchKernelGGL(gru_tr, dim3(T_N * 4), dim3(512), 0, stream,
                       x, Wih_f, Whh_f, bih_f, bhh_f, Wih_b, bih_b, bhh_b, Wfc, bfc, out);
}

// Round 15
// 100.534 us; speedup vs baseline: 1.8047x; 1.0534x over previous
//
#include <hip/hip_runtime.h>

// GRU via MFMA, round 15: restore round-12 champion (best measured: 93.5-94.4us
// kernel, 100.5us harness). B=128, S=144, T=50, I=10, H=64, O=1.
// pack_x pre-pass (bandwidth-bound, ~6.5us) + transposed-MFMA scan kernel:
// Grid = T * (B/32) = 200 wgs x 512 threads (8 waves), uniform <=1 wg/CU.
// A = weights (m = gate-unit), B = h/x (n = batch), D: row = unit, col = batch
// -> h-update store is one ds_write_b64. Weights+biases pre-scaled (r,z by
// -log2e; n by +2log2e) so exp2 args come straight from accumulators; 5-trans
// fused gates; f16 h double buffer; raw s_barrier + lgkmcnt-only wait.
//
// Session bracket (rounds 1-14): waves/tile {1,2,4,8}, barriers {hw,soft,none},
// sw-pipelining, chain-split, operand transpose, x-staging {LDS,regs,packed}.
// All alternatives tie or regress; scan is latency-bound on the serial
// 144-step h-recurrence (~1566 cy/step; HBM 5%, MfmaUtil 14%, VALUBusy 34%).
//
// MFMA 16x16x32 f16 layouts (gfx950, m89-verified):
//   A: m=lane&15, k=(lane>>4)*8+e;  B: n=lane&15, same k-map;
//   D: col=lane&15, row=(lane>>4)*4+reg.

typedef _Float16 f16;
typedef _Float16 f16x8 __attribute__((ext_vector_type(8)));
typedef _Float16 f16x4 __attribute__((ext_vector_type(4)));
typedef float    f32x4 __attribute__((ext_vector_type(4)));

constexpr int B_N = 128, S_N = 144, T_N = 50, I_N = 10, H_N = 64, G3 = 192;
constexpr int BT16 = 16, NB16 = B_N / BT16;
constexpr int HUW = 72;                 // h layout [batch16][unit64 + 8 pad] f16
constexpr int HST = 88;                 // fallback kernel stride
constexpr float L2E = 1.44269504089f;

#define MFMA16(a, b, c) __builtin_amdgcn_mfma_f32_16x16x32_f16((a), (b), (c), 0, 0, 0)

__device__ __forceinline__ float fsig(float v) {
    return __builtin_amdgcn_rcpf(1.0f + __builtin_amdgcn_exp2f(-L2E * v));
}
__device__ __forceinline__ float ftanh(float v) {
    return 1.0f - 2.0f * __builtin_amdgcn_rcpf(1.0f + __builtin_amdgcn_exp2f(2.0f * L2E * v));
}

// ---- x prep: xP[(b*S+s)*T+t][16] f16 = {x[0..9], 1.0, 0..0} ----
__global__ __launch_bounds__(256)
void pack_x(const float* __restrict__ x, f16* __restrict__ xP) {
    const int idx = blockIdx.x * 256 + threadIdx.x;
    if (idx >= B_N * S_N * T_N) return;
    const float* s = x + (size_t)idx * I_N;
    f16x8 lo, hi;
    #pragma unroll
    for (int e = 0; e < 8; ++e) lo[e] = (f16)s[e];
    hi[0] = (f16)s[8]; hi[1] = (f16)s[9]; hi[2] = (f16)1.0f;
    #pragma unroll
    for (int e = 3; e < 8; ++e) hi[e] = (f16)0.0f;
    f16* d = xP + (size_t)idx * 16;
    *(f16x8*)d = lo; *(f16x8*)(d + 8) = hi;
}

// ---- transposed paired-tile step: 9 MFMAs (weights in A slot), b64 h-store ----
// h' = [ (eC-1)*eB + h*(1+eC) ] * rcp( (1+eC)*(1+eB) )
#define STEPT(ss, xf)                                                             \
    {                                                                             \
        const int cur = (ss) & 1, nxt = cur ^ 1;                                  \
        const f16x8 xB = xf;                                                      \
        if ((ss) + 2 < S_N && lg < 2)                                             \
            xf = *(const f16x8*)(xProw + (size_t)((ss) + 2) * (T_N * 16) + lg * 8); \
        const f16* hrow = &hL[tile][cur][lc][0];                                  \
        const f16x8 hB0 = *(const f16x8*)(hrow + lg * 8);                         \
        const f16x8 hB1 = *(const f16x8*)(hrow + 32 + lg * 8);                    \
        f32x4 aR  = {0,0,0,0}, aZ = {0,0,0,0}, aNH = {0,0,0,0}, aNX = {0,0,0,0};  \
        aR  = MFMA16(WxR,  xB,  aR);                                              \
        aZ  = MFMA16(WxZ,  xB,  aZ);                                              \
        aNX = MFMA16(WxN,  xB,  aNX);                                             \
        aR  = MFMA16(WhR0, hB0, aR);                                              \
        aR  = MFMA16(WhR1, hB1, aR);                                              \
        aZ  = MFMA16(WhZ0, hB0, aZ);                                              \
        aZ  = MFMA16(WhZ1, hB1, aZ);                                              \
        aNH = MFMA16(WhN0, hB0, aNH);                                             \
        aNH = MFMA16(WhN1, hB1, aNH);                                             \
        f16x4 hv;                                                                 \
        _Pragma("unroll")                                                         \
        for (int j = 0; j < 4; ++j) {                                             \
            const float eA = __builtin_amdgcn_exp2f(aR[j]);                       \
            const float rr = __builtin_amdgcn_rcpf(1.0f + eA);                    \
            const float eB = __builtin_amdgcn_exp2f(aZ[j]);                       \
            const float eC = __builtin_amdgcn_exp2f(fmaf(rr, aNH[j] + bnhs4[j], aNX[j])); \
            const float v  = 1.0f + eC;                                           \
            const float ip = __builtin_amdgcn_rcpf(v * (1.0f + eB));              \
            const float p  = (eC - 1.0f) * eB;                                    \
            ho[j] = fmaf(ho[j], v, p) * ip;                                       \
            hv[j] = (f16)ho[j];                                                   \
        }                                                                         \
        *(f16x4*)(&hL[tile][nxt][lc][uc + lg * 4]) = hv;                          \
        asm volatile("s_waitcnt lgkmcnt(0)" ::: "memory");                        \
        __builtin_amdgcn_s_barrier();                                             \
        asm volatile("" ::: "memory");                                            \
    }

__global__ __launch_bounds__(512, 1)
void gru_tr(const f16* __restrict__ xP, const float* __restrict__ x,
            const float* __restrict__ Wih_f, const float* __restrict__ Whh_f,
            const float* __restrict__ bih_f, const float* __restrict__ bhh_f,
            const float* __restrict__ Wih_b, const float* __restrict__ bih_b,
            const float* __restrict__ bhh_b,
            const float* __restrict__ Wfc,   const float* __restrict__ bfc,
            float* __restrict__ out)
{
    __shared__ f16   hL[2][2][BT16][HUW];   // [tile][buf][batch row][unit] 9.2 KB
    __shared__ float hfL[2 * BT16][68];     // epilogue fwd h (f32), 16B-aligned rows
    __shared__ float hbL[2 * BT16][68];     // epilogue bwd h (f32)

    const int tid  = threadIdx.x;
    const int w    = tid >> 6, l = tid & 63;
    const int tile = w >> 2;            // 0 = rows b0.., 1 = rows b0+16..
    const int uc   = (w & 3) * 16;      // unit-block base 0,16,32,48
    const int lc   = l & 15;            // m (gate unit) for A; n (batch) for B/D-col
    const int lg   = l >> 4;            // k-group
    const int t    = blockIdx.x >> 2;          // turbine 0..49
    const int b0   = (blockIdx.x & 3) * 32 + tile * 16;

    // ---------------- prologue ----------------
    {
        f16* hp = &hL[0][0][0][0];
        for (int i = tid; i < 2 * 2 * BT16 * HUW; i += 512) hp[i] = (f16)0.0f;   // h0 = 0
    }

    const float* Whh = Whh_f + (size_t)t * G3 * H_N;
    const float* Wih = Wih_f + (size_t)t * G3 * I_N;
    const f16* xProw = xP + ((size_t)(b0 + lc) * S_N * T_N + t) * 16;

    // weight A-fragments (lane holds W[g0+lc][k=lg*8+e]), pre-scaled:
    // r,z by -log2e; n by +2log2e
    const float sRZ = -L2E, sN = 2.0f * L2E;
    auto loadWh = [&](int g, int kk, float sc) -> f16x8 {
        const float4* p = (const float4*)(Whh + (size_t)g * H_N + kk * 32 + lg * 8);
        const float4 a = p[0], b = p[1];
        f16x8 v;
        v[0] = (f16)(sc * a.x); v[1] = (f16)(sc * a.y); v[2] = (f16)(sc * a.z); v[3] = (f16)(sc * a.w);
        v[4] = (f16)(sc * b.x); v[5] = (f16)(sc * b.y); v[6] = (f16)(sc * b.z); v[7] = (f16)(sc * b.w);
        return v;
    };
    auto loadWx = [&](int g, bool rz, float sc) -> f16x8 {
        f16x8 v;
        #pragma unroll
        for (int j = 0; j < 8; ++j) {
            const int k = lg * 8 + j;
            float val = 0.0f;
            if (k < I_N)       val = Wih[(size_t)g * I_N + k];
            else if (k == 10)  val = bih_f[t * G3 + g] + (rz ? bhh_f[t * G3 + g] : 0.0f);
            v[j] = (f16)(sc * val);
        }
        return v;
    };

    const f16x8 WhR0 = loadWh(uc + lc, 0, sRZ),        WhR1 = loadWh(uc + lc, 1, sRZ);
    const f16x8 WhZ0 = loadWh(64 + uc + lc, 0, sRZ),   WhZ1 = loadWh(64 + uc + lc, 1, sRZ);
    const f16x8 WhN0 = loadWh(128 + uc + lc, 0, sN),   WhN1 = loadWh(128 + uc + lc, 1, sN);
    const f16x8 WxR  = loadWx(uc + lc, true, sRZ);
    const f16x8 WxZ  = loadWx(64 + uc + lc, true, sRZ);
    const f16x8 WxN  = loadWx(128 + uc + lc, false, sN);

    // n-gate hidden bias, per D-row (unit uc + lg*4 + j)
    float bnhs4[4];
    {
        const float4 bb = *(const float4*)(bhh_f + (size_t)t * G3 + 128 + uc + lg * 4);
        bnhs4[0] = sN * bb.x; bnhs4[1] = sN * bb.y; bnhs4[2] = sN * bb.z; bnhs4[3] = sN * bb.w;
    }

    // x B-fragments, depth 2 (lanes lg>=2 keep zeros; k slots 16..31 are zero)
    f16x8 xsA, xsB;
    #pragma unroll
    for (int e = 0; e < 8; ++e) { xsA[e] = (f16)0.0f; xsB[e] = (f16)0.0f; }
    if (lg < 2) {
        xsA = *(const f16x8*)(xProw + lg * 8);
        xsB = *(const f16x8*)(xProw + (size_t)(T_N * 16) + lg * 8);
    }

    float ho[4] = {0.f, 0.f, 0.f, 0.f};   // lane's h: units uc+lg*4+j, batch row lc

    __syncthreads();

    // ---------------- scan ----------------
    for (int s = 0; s < S_N; s += 2) {
        STEPT(s,     xsA)
        STEPT(s + 1, xsB)
    }

    // ---------------- epilogue ----------------
    {
        f32x4 hv = {ho[0], ho[1], ho[2], ho[3]};
        *(f32x4*)(&hfL[tile * BT16 + lc][uc + lg * 4]) = hv;
    }

    // backward cell: single step from h0=0 (=> Whh_b unused), on x[:, S-1, :].
    // 32 rows of this wg's batch quad; 16 threads/row, 4 units each.
    {
        const int row2 = tid >> 4;          // 0..31
        const int j0   = (tid & 15) * 4;
        const int bq   = (blockIdx.x & 3) * 32;
        const float* wib = Wih_b + (size_t)t * G3 * I_N;
        const float* bib = bih_b + t * G3;
        const float* bhb = bhh_b + t * G3;
        float2 xr[5];
        const float2* xp2 = (const float2*)(x + (((size_t)(bq + row2) * S_N + (S_N - 1)) * T_N + t) * I_N);
        #pragma unroll
        for (int k = 0; k < 5; ++k) xr[k] = xp2[k];
        #pragma unroll
        for (int m = 0; m < 4; ++m) {
            const int j = j0 + m;
            float ir = bib[j], iz = bib[64 + j], inn = bib[128 + j];
            const float2* wr = (const float2*)(wib + (size_t)j * I_N);
            const float2* wz = (const float2*)(wib + (size_t)(64 + j) * I_N);
            const float2* wn = (const float2*)(wib + (size_t)(128 + j) * I_N);
            #pragma unroll
            for (int k = 0; k < 5; ++k) {
                ir  = fmaf(wr[k].x, xr[k].x, fmaf(wr[k].y, xr[k].y, ir));
                iz  = fmaf(wz[k].x, xr[k].x, fmaf(wz[k].y, xr[k].y, iz));
                inn = fmaf(wn[k].x, xr[k].x, fmaf(wn[k].y, xr[k].y, inn));
            }
            const float r  = fsig(ir + bhb[j]);
            const float z  = fsig(iz + bhb[64 + j]);
            const float nn = ftanh(inn + r * bhb[128 + j]);
            hbL[row2][j] = (1.0f - z) * nn;   // h0 = 0
        }
    }
    __syncthreads();

    // FC: out[b,0,t] = [hf|hb] . Wfc[t,0,:] + bfc[t]
    if (tid < 2 * BT16) {
        const int bq = (blockIdx.x & 3) * 32;
        const float* wfc = Wfc + (size_t)t * 2 * H_N;
        float acc = bfc[t];
        #pragma unroll 4
        for (int j = 0; j < H_N; ++j) acc += hfL[tid][j] * wfc[j];
        #pragma unroll 4
        for (int j = 0; j < H_N; ++j) acc += hbL[tid][j] * wfc[64 + j];
        out[(size_t)(bq + tid) * T_N + t] = acc;
    }
}

// ================= fallback (no workspace): round-5 single-stream, raw x loads =================

#define LOADX_R(ss, q0, q1, q2, q3, q4)                                           \
    if ((ss) < S_N) {                                                             \
        const float* _p = x + (((size_t)(b0 + lc) * S_N + (ss)) * T_N + t) * I_N; \
        if (lg == 0) {                                                            \
            q0 = *(const float2*)(_p);     q1 = *(const float2*)(_p + 2);         \
            q2 = *(const float2*)(_p + 4); q3 = *(const float2*)(_p + 6);         \
        } else if (lg == 1) {                                                     \
            q4 = *(const float2*)(_p + 8);                                        \
        }                                                                         \
    }

#define STEP1(ss, q0, q1, q2, q3, q4)                                             \
    {                                                                             \
        const int cur = (ss) & 1, nxt = cur ^ 1;                                  \
        const f16* hrow = &hL[cur][lc][0];                                        \
        const f16x8 hA0 = *(const f16x8*)(hrow + lg * 8);                         \
        const f16x8 hA1 = *(const f16x8*)(hrow + 32 + lg * 8);                    \
        f16x8 xA;                                                                 \
        _Pragma("unroll")                                                         \
        for (int e = 0; e < 8; ++e) xA[e] = (f16)0.0f;                            \
        if (lg == 0) {                                                            \
            xA[0] = (f16)q0.x; xA[1] = (f16)q0.y; xA[2] = (f16)q1.x; xA[3] = (f16)q1.y; \
            xA[4] = (f16)q2.x; xA[5] = (f16)q2.y; xA[6] = (f16)q3.x; xA[7] = (f16)q3.y; \
        } else if (lg == 1) {                                                     \
            xA[0] = (f16)q4.x; xA[1] = (f16)q4.y; xA[2] = (f16)1.0f;              \
        }                                                                         \
        LOADX_R((ss) + 2, q0, q1, q2, q3, q4)                                     \
        f32x4 aR  = {0,0,0,0}, aZ = {0,0,0,0}, aNH = {0,0,0,0}, aNX = {0,0,0,0};  \
        aR  = MFMA16(xA,  BxR,  aR);                                              \
        aZ  = MFMA16(xA,  BxZ,  aZ);                                              \
        aNX = MFMA16(xA,  BxN,  aNX);                                             \
        aR  = MFMA16(hA0, BhR0, aR);                                              \
        aR  = MFMA16(hA1, BhR1, aR);                                              \
        aZ  = MFMA16(hA0, BhZ0, aZ);                                              \
        aZ  = MFMA16(hA1, BhZ1, aZ);                                              \
        aNH = MFMA16(hA0, BhN0, aNH);                                             \
        aNH = MFMA16(hA1, BhN1, aNH);                                             \
        const int r0 = lg * 4;                                                    \
        _Pragma("unroll")                                                         \
        for (int j = 0; j < 4; ++j) {                                             \
            const float rr = __builtin_amdgcn_rcpf(1.0f + __builtin_amdgcn_exp2f(aR[j])); \
            const float zz = __builtin_amdgcn_rcpf(1.0f + __builtin_amdgcn_exp2f(aZ[j])); \
            const float qq = __builtin_amdgcn_rcpf(1.0f + __builtin_amdgcn_exp2f(fmaf(rr, aNH[j] + bnhs, aNX[j]))); \
            const float nn = fmaf(-2.0f, qq, 1.0f);                               \
            ho[j] = fmaf(zz, ho[j] - nn, nn);                                     \
            hL[nxt][r0 + j][uc + lc] = (f16)ho[j];                                \
        }                                                                         \
        asm volatile("s_waitcnt lgkmcnt(0)" ::: "memory");                        \
        __builtin_amdgcn_s_barrier();                                             \
        asm volatile("" ::: "memory");                                            \
    }

__global__ __launch_bounds__(256, 2)
void gru_mfma1(const float* __restrict__ x,
               const float* __restrict__ Wih_f, const float* __restrict__ Whh_f,
               const float* __restrict__ bih_f, const float* __restrict__ bhh_f,
               const float* __restrict__ Wih_b, const float* __restrict__ bih_b,
               const float* __restrict__ bhh_b,
               const float* __restrict__ Wfc,   const float* __restrict__ bfc,
               float* __restrict__ out)
{
    __shared__ f16   hL[2][BT16][HST];
    __shared__ float hfL[BT16][H_N + 1];
    __shared__ float hbL[BT16][H_N + 1];

    const int tid = threadIdx.x;
    const int w   = tid >> 6, l = tid & 63;
    const int uc  = w * 16;
    const int lc  = l & 15;
    const int lg  = l >> 4;
    const int t   = blockIdx.x / NB16;
    const int b0  = (blockIdx.x % NB16) * BT16;

    {
        f16* hp = &hL[0][0][0];
        for (int i = tid; i < 2 * BT16 * HST; i += 256) hp[i] = (f16)0.0f;
    }

    const float* Whh = Whh_f + (size_t)t * G3 * H_N;
    const float* Wih = Wih_f + (size_t)t * G3 * I_N;

    const float sRZ = -L2E, sN = 2.0f * L2E;
    auto loadBh = [&](int g, int kk, float sc) -> f16x8 {
        const float4* p = (const float4*)(Whh + (size_t)g * H_N + kk * 32 + lg * 8);
        const float4 a = p[0], b = p[1];
        f16x8 v;
        v[0] = (f16)(sc * a.x); v[1] = (f16)(sc * a.y); v[2] = (f16)(sc * a.z); v[3] = (f16)(sc * a.w);
        v[4] = (f16)(sc * b.x); v[5] = (f16)(sc * b.y); v[6] = (f16)(sc * b.z); v[7] = (f16)(sc * b.w);
        return v;
    };
    auto loadBx = [&](int g, bool rz, float sc) -> f16x8 {
        f16x8 v;
        #pragma unroll
        for (int j = 0; j < 8; ++j) {
            const int k = lg * 8 + j;
            float val = 0.0f;
            if (k < I_N)       val = Wih[(size_t)g * I_N + k];
            else if (k == 10)  val = bih_f[t * G3 + g] + (rz ? bhh_f[t * G3 + g] : 0.0f);
            v[j] = (f16)(sc * val);
        }
        return v;
    };

    const f16x8 BhR0 = loadBh(uc + lc, 0, sRZ),        BhR1 = loadBh(uc + lc, 1, sRZ);
    const f16x8 BhZ0 = loadBh(64 + uc + lc, 0, sRZ),   BhZ1 = loadBh(64 + uc + lc, 1, sRZ);
    const f16x8 BhN0 = loadBh(128 + uc + lc, 0, sN),   BhN1 = loadBh(128 + uc + lc, 1, sN);
    const f16x8 BxR  = loadBx(uc + lc, true, sRZ);
    const f16x8 BxZ  = loadBx(64 + uc + lc, true, sRZ);
    const f16x8 BxN  = loadBx(128 + uc + lc, false, sN);
    const float bnhs = sN * bhh_f[t * G3 + 128 + uc + lc];

    float2 ra0 = {0.f,0.f}, ra1 = {0.f,0.f}, ra2 = {0.f,0.f}, ra3 = {0.f,0.f}, ra4 = {0.f,0.f};
    float2 rb0 = {0.f,0.f}, rb1 = {0.f,0.f}, rb2 = {0.f,0.f}, rb3 = {0.f,0.f}, rb4 = {0.f,0.f};
    LOADX_R(0, ra0, ra1, ra2, ra3, ra4)
    LOADX_R(1, rb0, rb1, rb2, rb3, rb4)

    float ho[4] = {0.f, 0.f, 0.f, 0.f};

    __syncthreads();

    for (int s = 0; s < S_N; s += 2) {
        STEP1(s,     ra0, ra1, ra2, ra3, ra4)
        STEP1(s + 1, rb0, rb1, rb2, rb3, rb4)
    }

    {
        const int r0 = lg * 4;
        #pragma unroll
        for (int j = 0; j < 4; ++j) hfL[r0 + j][uc + lc] = ho[j];
    }

    {
        const int row2 = tid >> 4;
        const int j0   = (tid & 15) * 4;
        const float* wib = Wih_b + (size_t)t * G3 * I_N;
        const float* bib = bih_b + t * G3;
        const float* bhb = bhh_b + t * G3;
        float xr[I_N];
        #pragma unroll
        for (int k = 0; k < I_N; ++k)
            xr[k] = x[(((size_t)(b0 + row2) * S_N + (S_N - 1)) * T_N + t) * I_N + k];
        #pragma unroll
        for (int m = 0; m < 4; ++m) {
            const int j = j0 + m;
            float ir = bib[j], iz = bib[64 + j], inn = bib[128 + j];
            #pragma unroll
            for (int k = 0; k < I_N; ++k) {
                const float xv = xr[k];
                ir  += wib[(size_t)j * I_N + k]          * xv;
                iz  += wib[(size_t)(64 + j) * I_N + k]   * xv;
                inn += wib[(size_t)(128 + j) * I_N + k]  * xv;
            }
            const float r  = fsig(ir + bhb[j]);
            const float z  = fsig(iz + bhb[64 + j]);
            const float nn = ftanh(inn + r * bhb[128 + j]);
            hbL[row2][j] = (1.0f - z) * nn;
        }
    }
    __syncthreads();

    if (tid < BT16) {
        const float* wfc = Wfc + (size_t)t * 2 * H_N;
        float acc = bfc[t];
        #pragma unroll 4
        for (int j = 0; j < H_N; ++j) acc += hfL[tid][j] * wfc[j];
        #pragma unroll 4
        for (int j = 0; j < H_N; ++j) acc += hbL[tid][j] * wfc[64 + j];
        out[(size_t)(b0 + tid) * T_N + t] = acc;
    }
}

extern "C" void kernel_launch(void* const* d_in, const int* in_sizes, int n_in,
                              void* d_out, int out_size, void* d_ws, size_t ws_size,
                              hipStream_t stream) {
    const float* x     = (const float*)d_in[0];
    const float* Wih_f = (const float*)d_in[1];
    const float* Whh_f = (const float*)d_in[2];
    const float* bih_f = (const float*)d_in[3];
    const float* bhh_f = (const float*)d_in[4];
    const float* Wih_b = (const float*)d_in[5];
    // d_in[6] = Whh_b: unused (backward cell runs one step from h0 == 0).
    const float* bih_b = (const float*)d_in[7];
    const float* bhh_b = (const float*)d_in[8];
    const float* Wfc   = (const float*)d_in[9];
    const float* bfc   = (const float*)d_in[10];
    float* out = (float*)d_out;

    const size_t xp_bytes = (size_t)B_N * S_N * T_N * 16 * sizeof(f16);  // 29.5 MB

    if (ws_size >= xp_bytes) {
        f16* xP = (f16*)d_ws;
        const int n = B_N * S_N * T_N;
        hipLaunchKernelGGL(pack_x, dim3((n + 255) / 256), dim3(256), 0, stream, x, xP);
        hipLaunchKernelGGL(gru_tr, dim3(T_N * 4), dim3(512), 0, stream,
                           xP, x, Wih_f, Whh_f, bih_f, bhh_f, Wih_b, bih_b, bhh_b, Wfc, bfc, out);
    } else {
        hipLaunchKernelGGL(gru_mfma1, dim3(T_N * NB16), dim3(256), 0, stream,
                           x, Wih_f, Whh_f, bih_f, bhh_f, Wih_b, bih_b, bhh_b, Wfc, bfc, out);
    }
}